// Round 1
// baseline (832.756 us; speedup 1.0000x reference)
//
#include <hip/hip_runtime.h>

#define B_ 8
#define S_ 1024
#define E_ 1024
#define H_ 16
#define D_ 64

typedef __attribute__((ext_vector_type(8))) __bf16 bf16x8;
typedef __attribute__((ext_vector_type(4))) float f32x4;
typedef __attribute__((ext_vector_type(4))) unsigned short u16x4;
typedef __attribute__((ext_vector_type(8))) unsigned short u16x8;

static __device__ __forceinline__ unsigned short f2bf(float f) {
  union { float f; unsigned int u; } v; v.f = f;
  unsigned int r = v.u + 0x7FFFu + ((v.u >> 16) & 1u);  // RNE
  return (unsigned short)(r >> 16);
}

#define MFMA16(a, b, c) __builtin_amdgcn_mfma_f32_16x16x32_bf16((a), (b), (c), 0, 0, 0)

// ---------------- cast h (fp32 -> bf16), vectorized ----------------
__global__ void cast_f32_bf16_kernel(const float* __restrict__ src,
                                     unsigned short* __restrict__ dst, int n4) {
  int i = blockIdx.x * 256 + threadIdx.x;
  if (i >= n4) return;
  float4 v = reinterpret_cast<const float4*>(src)[i];
  u16x4 o;
  o[0] = f2bf(v.x); o[1] = f2bf(v.y); o[2] = f2bf(v.z); o[3] = f2bf(v.w);
  reinterpret_cast<u16x4*>(dst)[i] = o;
}

// ---------------- transpose + cast: dst[c][r] = bf16(src[r][c]) ----------------
// grid: (cols/64, rows/64, nmat), block 256
__global__ void transpose_cast_kernel(const float* __restrict__ src,
                                      unsigned short* __restrict__ dst,
                                      int rows, int cols) {
  __shared__ unsigned short tile[64][65];
  const float* s = src + (size_t)blockIdx.z * rows * cols;
  unsigned short* d = dst + (size_t)blockIdx.z * rows * cols;
  int rb = blockIdx.y * 64, cb = blockIdx.x * 64;
#pragma unroll
  for (int k = 0; k < 16; k++) {
    int idx = threadIdx.x + 256 * k;
    int r = idx >> 6, c = idx & 63;
    tile[r][c] = f2bf(s[(size_t)(rb + r) * cols + cb + c]);
  }
  __syncthreads();
#pragma unroll
  for (int k = 0; k < 16; k++) {
    int idx = threadIdx.x + 256 * k;
    int r = idx >> 6, c = idx & 63;   // r = output row (a col of src)
    d[(size_t)(cb + r) * rows + rb + c] = tile[c][r];
  }
}

// ---------------- G^T: GT[b][e][t] = sum_ein h[b][t][ein] * Wo[ein][e] ----------------
// grid (8 mblk(t), 8 nblk(e), B), block 256 (4 waves as 2x2, wave tile 64x64)
__launch_bounds__(256)
__global__ void gemm_G_kernel(const unsigned short* __restrict__ hb,
                              const unsigned short* __restrict__ WoT,  // [E][E] (e, ein)
                              unsigned short* __restrict__ GT) {       // [B][E][S]
  int mblk = blockIdx.x, nblk = blockIdx.y, b = blockIdx.z;
  const unsigned short* A = hb + (size_t)b * S_ * E_;
  int tid = threadIdx.x, l = tid & 63, w = tid >> 6;
  int ws = w & 1, wc = w >> 1, lr = l & 15, lg = l >> 4;
  f32x4 acc[4][4] = {};
  int ar[4], bc[4];
#pragma unroll
  for (int i = 0; i < 4; i++) ar[i] = mblk * 128 + ws * 64 + i * 16 + lr;
#pragma unroll
  for (int j = 0; j < 4; j++) bc[j] = nblk * 128 + wc * 64 + j * 16 + lr;
  for (int k0 = 0; k0 < E_; k0 += 32) {
    bf16x8 a[4], bb[4];
#pragma unroll
    for (int i = 0; i < 4; i++)
      a[i] = *reinterpret_cast<const bf16x8*>(A + (size_t)ar[i] * E_ + k0 + lg * 8);
#pragma unroll
    for (int j = 0; j < 4; j++)
      bb[j] = *reinterpret_cast<const bf16x8*>(WoT + (size_t)bc[j] * E_ + k0 + lg * 8);
#pragma unroll
    for (int i = 0; i < 4; i++)
#pragma unroll
      for (int j = 0; j < 4; j++)
        acc[i][j] = MFMA16(a[i], bb[j], acc[i][j]);
  }
#pragma unroll
  for (int i = 0; i < 4; i++) {
    int t0 = mblk * 128 + ws * 64 + i * 16 + lg * 4;
#pragma unroll
    for (int j = 0; j < 4; j++) {
      u16x4 p;
#pragma unroll
      for (int r = 0; r < 4; r++) p[r] = f2bf(acc[i][j][r]);
      *reinterpret_cast<u16x4*>(GT + ((size_t)b * E_ + bc[j]) * S_ + t0) = p;
    }
  }
}

// ---------------- Q/K projection: out[z][s][d] = h[b] @ W[h] + bias[h] ----------------
// grid (8 sblk, B*H), block 256; wave tile 64x32
__launch_bounds__(256)
__global__ void proj_kernel(const unsigned short* __restrict__ hb,
                            const unsigned short* __restrict__ WT,   // [H][D][E]
                            const float* __restrict__ bias,          // [H][D]
                            unsigned short* __restrict__ out) {      // [B*H][S][D]
  int sblk = blockIdx.x, z = blockIdx.y;
  int b = z >> 4, h = z & 15;
  const unsigned short* A = hb + (size_t)b * S_ * E_;
  const unsigned short* Bt = WT + (size_t)h * D_ * E_;
  const float* bh = bias + h * D_;
  unsigned short* ob = out + (size_t)z * S_ * D_;
  int tid = threadIdx.x, l = tid & 63, w = tid >> 6;
  int ws = w & 1, wc = w >> 1, lr = l & 15, lg = l >> 4;
  f32x4 acc[4][2] = {};
  int ar[4], bc[2];
#pragma unroll
  for (int i = 0; i < 4; i++) ar[i] = sblk * 128 + ws * 64 + i * 16 + lr;
#pragma unroll
  for (int j = 0; j < 2; j++) bc[j] = wc * 32 + j * 16 + lr;
  for (int k0 = 0; k0 < E_; k0 += 32) {
    bf16x8 a[4], bb[2];
#pragma unroll
    for (int i = 0; i < 4; i++)
      a[i] = *reinterpret_cast<const bf16x8*>(A + (size_t)ar[i] * E_ + k0 + lg * 8);
#pragma unroll
    for (int j = 0; j < 2; j++)
      bb[j] = *reinterpret_cast<const bf16x8*>(Bt + (size_t)bc[j] * E_ + k0 + lg * 8);
#pragma unroll
    for (int i = 0; i < 4; i++)
#pragma unroll
      for (int j = 0; j < 2; j++)
        acc[i][j] = MFMA16(a[i], bb[j], acc[i][j]);
  }
  float bv[2];
#pragma unroll
  for (int j = 0; j < 2; j++) bv[j] = bh[bc[j]];
#pragma unroll
  for (int i = 0; i < 4; i++)
#pragma unroll
    for (int j = 0; j < 2; j++)
#pragma unroll
      for (int r = 0; r < 4; r++) {
        int s = sblk * 128 + ws * 64 + i * 16 + lg * 4 + r;
        ob[(size_t)s * D_ + bc[j]] = f2bf(acc[i][j][r] + bv[j]);
      }
}

// ---------------- column logsumexp stats: c[z][t] over s ----------------
// grid (S/256, B*H), block 256; wave handles 64 t-cols
__launch_bounds__(256)
__global__ void stats_kernel(const unsigned short* __restrict__ Qb,
                             const unsigned short* __restrict__ Kb,
                             float* __restrict__ c) {
  int tblk = blockIdx.x, z = blockIdx.y;
  const unsigned short* Q = Qb + (size_t)z * S_ * D_;
  const unsigned short* K = Kb + (size_t)z * S_ * D_;
  int tid = threadIdx.x, l = tid & 63, w = tid >> 6;
  int lr = l & 15, lg = l >> 4;
  int tb = tblk * 256 + w * 64;
  const float scale = 0.125f;
  bf16x8 kb[4][2];
#pragma unroll
  for (int j = 0; j < 4; j++)
#pragma unroll
    for (int ks = 0; ks < 2; ks++)
      kb[j][ks] = *reinterpret_cast<const bf16x8*>(
          K + (size_t)(tb + j * 16 + lr) * D_ + ks * 32 + lg * 8);
  float m[4], zz[4];
#pragma unroll
  for (int j = 0; j < 4; j++) { m[j] = -1e30f; zz[j] = 0.f; }
  for (int s0 = 0; s0 < S_; s0 += 32) {
    bf16x8 aq[2][2];
#pragma unroll
    for (int sf = 0; sf < 2; sf++)
#pragma unroll
      for (int ks = 0; ks < 2; ks++)
        aq[sf][ks] = *reinterpret_cast<const bf16x8*>(
            Q + (size_t)(s0 + sf * 16 + lr) * D_ + ks * 32 + lg * 8);
    f32x4 acc[2][4] = {};
#pragma unroll
    for (int sf = 0; sf < 2; sf++)
#pragma unroll
      for (int j = 0; j < 4; j++) {
        acc[sf][j] = MFMA16(aq[sf][0], kb[j][0], acc[sf][j]);
        acc[sf][j] = MFMA16(aq[sf][1], kb[j][1], acc[sf][j]);
      }
#pragma unroll
    for (int j = 0; j < 4; j++) {
      float v[8];
#pragma unroll
      for (int sf = 0; sf < 2; sf++)
#pragma unroll
        for (int r = 0; r < 4; r++) v[sf * 4 + r] = acc[sf][j][r] * scale;
      float mx = m[j];
#pragma unroll
      for (int t = 0; t < 8; t++) mx = fmaxf(mx, v[t]);
      float sum = 0.f;
#pragma unroll
      for (int t = 0; t < 8; t++) sum += __expf(v[t] - mx);
      zz[j] = zz[j] * __expf(m[j] - mx) + sum;
      m[j] = mx;
    }
  }
#pragma unroll
  for (int j = 0; j < 4; j++) {
    float mj = m[j], zj = zz[j];
#pragma unroll
    for (int off = 16; off <= 32; off <<= 1) {
      float om = __shfl_xor(mj, off, 64);
      float oz = __shfl_xor(zj, off, 64);
      float mn = fmaxf(mj, om);
      zj = zj * __expf(mj - mn) + oz * __expf(om - mn);
      mj = mn;
    }
    if (l < 16) c[(size_t)z * S_ + tb + j * 16 + lr] = mj + __logf(zj);
  }
}

// ---------------- fused: out[b, h*S+s, e] = sum_t exp(scale*q.k - c_t) * G[t][e] + bo[e] ----
// grid (8 sblk, 4 eblk, B*H), block 256
__launch_bounds__(256, 2)
__global__ void attn_kernel(const unsigned short* __restrict__ Qb,
                            const unsigned short* __restrict__ Kb,
                            const unsigned short* __restrict__ GT,  // [B][E][S]
                            const float* __restrict__ cst,          // [B*H][S]
                            const float* __restrict__ bo,
                            float* __restrict__ out) {
  int sblk = blockIdx.x, eblk = blockIdx.y, z = blockIdx.z;
  int b = z >> 4, h = z & 15;
  __shared__ unsigned short Qs[128][72];
  __shared__ unsigned short Ks[32][72];
  __shared__ unsigned short Gs[256][40];
  __shared__ unsigned short Ps[128][40];
  int tid = threadIdx.x, l = tid & 63, w = tid >> 6;
  int lr = l & 15, lg = l >> 4;
  int ws = w & 1, we = w >> 1;
  const unsigned short* Q = Qb + (size_t)z * S_ * D_ + (size_t)sblk * 128 * D_;
  const unsigned short* K = Kb + (size_t)z * S_ * D_;
  const unsigned short* G = GT + ((size_t)b * E_ + eblk * 256) * S_;
  const float* cz = cst + (size_t)z * S_;
  const float scale = 0.125f;

  // stage Q tile [128][64]
#pragma unroll
  for (int i = 0; i < 4; i++) {
    int cid = tid + 256 * i;
    int row = cid >> 3, c8 = (cid & 7) * 8;
    *reinterpret_cast<u16x8*>(&Qs[row][c8]) =
        *reinterpret_cast<const u16x8*>(Q + row * D_ + c8);
  }

  f32x4 acc[4][8] = {};

  for (int t0 = 0; t0 < S_; t0 += 32) {
    __syncthreads();   // prior-iter LDS reads done (also covers Q staging on iter 0)
    {  // stage K tile [32][64]
      int row = tid >> 3, c8 = (tid & 7) * 8;
      *reinterpret_cast<u16x8*>(&Ks[row][c8]) =
          *reinterpret_cast<const u16x8*>(K + (size_t)(t0 + row) * D_ + c8);
    }
#pragma unroll
    for (int i = 0; i < 4; i++) {  // stage G^T tile [256][32]
      int cid = tid + 256 * i;
      int row = cid >> 2, c8 = (cid & 3) * 8;
      *reinterpret_cast<u16x8*>(&Gs[row][c8]) =
          *reinterpret_cast<const u16x8*>(G + (size_t)row * S_ + t0 + c8);
    }
    __syncthreads();

    {  // scores^T = K·Q^T for s rows [w*32, w*32+32): lane holds 4 consecutive t
      bf16x8 ka[2][2], qb[2][2];
#pragma unroll
      for (int tf = 0; tf < 2; tf++)
#pragma unroll
        for (int ks = 0; ks < 2; ks++)
          ka[tf][ks] = *reinterpret_cast<const bf16x8*>(&Ks[tf * 16 + lr][ks * 32 + lg * 8]);
#pragma unroll
      for (int sf = 0; sf < 2; sf++)
#pragma unroll
        for (int ks = 0; ks < 2; ks++)
          qb[sf][ks] = *reinterpret_cast<const bf16x8*>(&Qs[w * 32 + sf * 16 + lr][ks * 32 + lg * 8]);
      f32x4 sa[2][2] = {};
#pragma unroll
      for (int tf = 0; tf < 2; tf++)
#pragma unroll
        for (int sf = 0; sf < 2; sf++) {
          sa[tf][sf] = MFMA16(ka[tf][0], qb[sf][0], sa[tf][sf]);
          sa[tf][sf] = MFMA16(ka[tf][1], qb[sf][1], sa[tf][sf]);
        }
#pragma unroll
      for (int tf = 0; tf < 2; tf++) {
        f32x4 cv = *reinterpret_cast<const f32x4*>(cz + t0 + tf * 16 + lg * 4);
#pragma unroll
        for (int sf = 0; sf < 2; sf++) {
          u16x4 p;
#pragma unroll
          for (int r = 0; r < 4; r++)
            p[r] = f2bf(__expf(sa[tf][sf][r] * scale - cv[r]));
          *reinterpret_cast<u16x4*>(&Ps[w * 32 + sf * 16 + lr][tf * 16 + lg * 4]) = p;
        }
      }
    }
    __syncthreads();

    {  // PV: wave (ws,we) owns s [ws*64,+64) x e [we*128,+128)
      bf16x8 ap[4], bg[8];
#pragma unroll
      for (int i = 0; i < 4; i++)
        ap[i] = *reinterpret_cast<const bf16x8*>(&Ps[ws * 64 + i * 16 + lr][lg * 8]);
#pragma unroll
      for (int j = 0; j < 8; j++)
        bg[j] = *reinterpret_cast<const bf16x8*>(&Gs[we * 128 + j * 16 + lr][lg * 8]);
#pragma unroll
      for (int i = 0; i < 4; i++)
#pragma unroll
        for (int j = 0; j < 8; j++)
          acc[i][j] = MFMA16(ap[i], bg[j], acc[i][j]);
    }
  }

  // epilogue: out[b][h*S + s][e] = acc + bo[e]
  float bov[8];
#pragma unroll
  for (int j = 0; j < 8; j++) bov[j] = bo[eblk * 256 + we * 128 + j * 16 + lr];
#pragma unroll
  for (int i = 0; i < 4; i++)
#pragma unroll
    for (int j = 0; j < 8; j++)
#pragma unroll
      for (int r = 0; r < 4; r++) {
        int srow = sblk * 128 + ws * 64 + i * 16 + lg * 4 + r;
        size_t R = (size_t)h * S_ + srow;
        int col = eblk * 256 + we * 128 + j * 16 + lr;
        out[((size_t)b * (H_ * S_) + R) * E_ + col] = acc[i][j][r] + bov[j];
      }
}

extern "C" void kernel_launch(void* const* d_in, const int* in_sizes, int n_in,
                              void* d_out, int out_size, void* d_ws, size_t ws_size,
                              hipStream_t stream) {
  const float* h  = (const float*)d_in[0];
  const float* Wq = (const float*)d_in[1];
  const float* bq = (const float*)d_in[2];
  const float* Wk = (const float*)d_in[3];
  const float* bk = (const float*)d_in[4];
  // d_in[5] = Wv, d_in[6] = bv: dead weights in the reference
  const float* Wo = (const float*)d_in[7];
  const float* bo = (const float*)d_in[8];
  float* out = (float*)d_out;

  char* p = (char*)d_ws;
  unsigned short* hb  = (unsigned short*)p; p += (size_t)B_ * S_ * E_ * 2;
  unsigned short* WoT = (unsigned short*)p; p += (size_t)E_ * E_ * 2;
  unsigned short* WqT = (unsigned short*)p; p += (size_t)H_ * D_ * E_ * 2;
  unsigned short* WkT = (unsigned short*)p; p += (size_t)H_ * D_ * E_ * 2;
  unsigned short* Qb  = (unsigned short*)p; p += (size_t)B_ * H_ * S_ * D_ * 2;
  unsigned short* Kb  = (unsigned short*)p; p += (size_t)B_ * H_ * S_ * D_ * 2;
  unsigned short* GT  = (unsigned short*)p; p += (size_t)B_ * E_ * S_ * 2;
  float*          cst = (float*)p;          p += (size_t)B_ * H_ * S_ * 4;

  int n4 = B_ * S_ * E_ / 4;
  cast_f32_bf16_kernel<<<dim3(n4 / 256), 256, 0, stream>>>(h, hb, n4);
  transpose_cast_kernel<<<dim3(16, 16, 1), 256, 0, stream>>>(Wo, WoT, E_, E_);
  transpose_cast_kernel<<<dim3(1, 16, H_), 256, 0, stream>>>(Wq, WqT, E_, D_);
  transpose_cast_kernel<<<dim3(1, 16, H_), 256, 0, stream>>>(Wk, WkT, E_, D_);
  gemm_G_kernel<<<dim3(8, 8, B_), 256, 0, stream>>>(hb, WoT, GT);
  proj_kernel<<<dim3(8, B_ * H_), 256, 0, stream>>>(hb, WqT, bq, Qb);
  proj_kernel<<<dim3(8, B_ * H_), 256, 0, stream>>>(hb, WkT, bk, Kb);
  stats_kernel<<<dim3(S_ / 256, B_ * H_), 256, 0, stream>>>(Qb, Kb, cst);
  attn_kernel<<<dim3(8, 4, B_ * H_), 256, 0, stream>>>(Qb, Kb, GT, cst, bo, out);
}

// Round 2
// 691.197 us; speedup vs baseline: 1.2048x; 1.2048x over previous
//
#include <hip/hip_runtime.h>

#define B_ 8
#define S_ 1024
#define E_ 1024
#define H_ 16
#define D_ 64

typedef __attribute__((ext_vector_type(8))) __bf16 bf16x8;
typedef __attribute__((ext_vector_type(4))) float f32x4;
typedef __attribute__((ext_vector_type(4))) unsigned short u16x4;
typedef __attribute__((ext_vector_type(8))) unsigned short u16x8;

static __device__ __forceinline__ unsigned short f2bf(float f) {
  union { float f; unsigned int u; } v; v.f = f;
  unsigned int r = v.u + 0x7FFFu + ((v.u >> 16) & 1u);  // RNE
  return (unsigned short)(r >> 16);
}

#define MFMA16(a, b, c) __builtin_amdgcn_mfma_f32_16x16x32_bf16((a), (b), (c), 0, 0, 0)

// ---------------- cast h (fp32 -> bf16), vectorized ----------------
__global__ void cast_f32_bf16_kernel(const float* __restrict__ src,
                                     unsigned short* __restrict__ dst, int n4) {
  int i = blockIdx.x * 256 + threadIdx.x;
  if (i >= n4) return;
  float4 v = reinterpret_cast<const float4*>(src)[i];
  u16x4 o;
  o[0] = f2bf(v.x); o[1] = f2bf(v.y); o[2] = f2bf(v.z); o[3] = f2bf(v.w);
  reinterpret_cast<u16x4*>(dst)[i] = o;
}

// ---------------- transpose + cast: dst[c][r] = bf16(src[r][c]) ----------------
__global__ void transpose_cast_kernel(const float* __restrict__ src,
                                      unsigned short* __restrict__ dst,
                                      int rows, int cols) {
  __shared__ unsigned short tile[64][65];
  const float* s = src + (size_t)blockIdx.z * rows * cols;
  unsigned short* d = dst + (size_t)blockIdx.z * rows * cols;
  int rb = blockIdx.y * 64, cb = blockIdx.x * 64;
#pragma unroll
  for (int k = 0; k < 16; k++) {
    int idx = threadIdx.x + 256 * k;
    int r = idx >> 6, c = idx & 63;
    tile[r][c] = f2bf(s[(size_t)(rb + r) * cols + cb + c]);
  }
  __syncthreads();
#pragma unroll
  for (int k = 0; k < 16; k++) {
    int idx = threadIdx.x + 256 * k;
    int r = idx >> 6, c = idx & 63;
    d[(size_t)(cb + r) * rows + rb + c] = tile[c][r];
  }
}

// ---------------- G^T tiled: Gt[b][e/256][t/32][e%256][t%32] = (h@Wo)^T ----------------
// grid (8 mblk(t), 8 nblk(e), B), block 256 (4 waves as 2x2, wave tile 64x64)
__launch_bounds__(256)
__global__ void gemm_G_kernel(const unsigned short* __restrict__ hb,
                              const unsigned short* __restrict__ WoT,  // [E][E] (e, ein)
                              unsigned short* __restrict__ Gt) {
  int mblk = blockIdx.x, nblk = blockIdx.y, b = blockIdx.z;
  const unsigned short* A = hb + (size_t)b * S_ * E_;
  int tid = threadIdx.x, l = tid & 63, w = tid >> 6;
  int ws = w & 1, wc = w >> 1, lr = l & 15, lg = l >> 4;
  f32x4 acc[4][4] = {};
  int ar[4], bc[4];
#pragma unroll
  for (int i = 0; i < 4; i++) ar[i] = mblk * 128 + ws * 64 + i * 16 + lr;
#pragma unroll
  for (int j = 0; j < 4; j++) bc[j] = nblk * 128 + wc * 64 + j * 16 + lr;
  for (int k0 = 0; k0 < E_; k0 += 32) {
    bf16x8 a[4], bb[4];
#pragma unroll
    for (int i = 0; i < 4; i++)
      a[i] = *reinterpret_cast<const bf16x8*>(A + (size_t)ar[i] * E_ + k0 + lg * 8);
#pragma unroll
    for (int j = 0; j < 4; j++)
      bb[j] = *reinterpret_cast<const bf16x8*>(WoT + (size_t)bc[j] * E_ + k0 + lg * 8);
#pragma unroll
    for (int i = 0; i < 4; i++)
#pragma unroll
      for (int j = 0; j < 4; j++)
        acc[i][j] = MFMA16(a[i], bb[j], acc[i][j]);
  }
#pragma unroll
  for (int i = 0; i < 4; i++) {
    int t0 = mblk * 128 + ws * 64 + i * 16 + lg * 4;
#pragma unroll
    for (int j = 0; j < 4; j++) {
      u16x4 p;
#pragma unroll
      for (int r = 0; r < 4; r++) p[r] = f2bf(acc[i][j][r]);
      int e = bc[j];
      size_t addr = (((size_t)b * 4 + (e >> 8)) * 32 + (t0 >> 5)) * 8192 +
                    (size_t)(e & 255) * 32 + (t0 & 31);
      *reinterpret_cast<u16x4*>(Gt + addr) = p;
    }
  }
}

// ---------------- fused Q&K projection ----------------
// grid (8 sblk, B*H), block 256; wave tile 64x32; both heads' Q and K per pass
__launch_bounds__(256)
__global__ void proj_qk_kernel(const unsigned short* __restrict__ hb,
                               const unsigned short* __restrict__ WqT,  // [H][D][E]
                               const unsigned short* __restrict__ WkT,
                               const float* __restrict__ bq,            // [H][D]
                               const float* __restrict__ bk,
                               unsigned short* __restrict__ Qb,         // [B*H][S][D]
                               unsigned short* __restrict__ Kb) {
  int sblk = blockIdx.x, z = blockIdx.y;
  int b = z >> 4, h = z & 15;
  const unsigned short* A = hb + (size_t)b * S_ * E_;
  const unsigned short* Btq = WqT + (size_t)h * D_ * E_;
  const unsigned short* Btk = WkT + (size_t)h * D_ * E_;
  int tid = threadIdx.x, l = tid & 63, w = tid >> 6;
  int ws = w & 1, wc = w >> 1, lr = l & 15, lg = l >> 4;
  f32x4 accq[4][2] = {}, acck[4][2] = {};
  int ar[4], bc[2];
#pragma unroll
  for (int i = 0; i < 4; i++) ar[i] = sblk * 128 + ws * 64 + i * 16 + lr;
#pragma unroll
  for (int j = 0; j < 2; j++) bc[j] = wc * 32 + j * 16 + lr;
  for (int k0 = 0; k0 < E_; k0 += 32) {
    bf16x8 a[4], bbq[2], bbk[2];
#pragma unroll
    for (int i = 0; i < 4; i++)
      a[i] = *reinterpret_cast<const bf16x8*>(A + (size_t)ar[i] * E_ + k0 + lg * 8);
#pragma unroll
    for (int j = 0; j < 2; j++) {
      bbq[j] = *reinterpret_cast<const bf16x8*>(Btq + (size_t)bc[j] * E_ + k0 + lg * 8);
      bbk[j] = *reinterpret_cast<const bf16x8*>(Btk + (size_t)bc[j] * E_ + k0 + lg * 8);
    }
#pragma unroll
    for (int i = 0; i < 4; i++)
#pragma unroll
      for (int j = 0; j < 2; j++) {
        accq[i][j] = MFMA16(a[i], bbq[j], accq[i][j]);
        acck[i][j] = MFMA16(a[i], bbk[j], acck[i][j]);
      }
  }
  unsigned short* oq = Qb + (size_t)z * S_ * D_;
  unsigned short* ok = Kb + (size_t)z * S_ * D_;
#pragma unroll
  for (int j = 0; j < 2; j++) {
    float bvq = bq[h * D_ + bc[j]], bvk = bk[h * D_ + bc[j]];
#pragma unroll
    for (int i = 0; i < 4; i++)
#pragma unroll
      for (int r = 0; r < 4; r++) {
        int s = sblk * 128 + ws * 64 + i * 16 + lg * 4 + r;
        oq[(size_t)s * D_ + bc[j]] = f2bf(accq[i][j][r] + bvq);
        ok[(size_t)s * D_ + bc[j]] = f2bf(acck[i][j][r] + bvk);
      }
  }
}

// ---------------- column logsumexp stats: c[z][t] over s ----------------
__launch_bounds__(256)
__global__ void stats_kernel(const unsigned short* __restrict__ Qb,
                             const unsigned short* __restrict__ Kb,
                             float* __restrict__ c) {
  int tblk = blockIdx.x, z = blockIdx.y;
  const unsigned short* Q = Qb + (size_t)z * S_ * D_;
  const unsigned short* K = Kb + (size_t)z * S_ * D_;
  int tid = threadIdx.x, l = tid & 63, w = tid >> 6;
  int lr = l & 15, lg = l >> 4;
  int tb = tblk * 256 + w * 64;
  const float scale = 0.125f;
  bf16x8 kb[4][2];
#pragma unroll
  for (int j = 0; j < 4; j++)
#pragma unroll
    for (int ks = 0; ks < 2; ks++)
      kb[j][ks] = *reinterpret_cast<const bf16x8*>(
          K + (size_t)(tb + j * 16 + lr) * D_ + ks * 32 + lg * 8);
  float m[4], zz[4];
#pragma unroll
  for (int j = 0; j < 4; j++) { m[j] = -1e30f; zz[j] = 0.f; }
  for (int s0 = 0; s0 < S_; s0 += 32) {
    bf16x8 aq[2][2];
#pragma unroll
    for (int sf = 0; sf < 2; sf++)
#pragma unroll
      for (int ks = 0; ks < 2; ks++)
        aq[sf][ks] = *reinterpret_cast<const bf16x8*>(
            Q + (size_t)(s0 + sf * 16 + lr) * D_ + ks * 32 + lg * 8);
    f32x4 acc[2][4] = {};
#pragma unroll
    for (int sf = 0; sf < 2; sf++)
#pragma unroll
      for (int j = 0; j < 4; j++) {
        acc[sf][j] = MFMA16(aq[sf][0], kb[j][0], acc[sf][j]);
        acc[sf][j] = MFMA16(aq[sf][1], kb[j][1], acc[sf][j]);
      }
#pragma unroll
    for (int j = 0; j < 4; j++) {
      float v[8];
#pragma unroll
      for (int sf = 0; sf < 2; sf++)
#pragma unroll
        for (int r = 0; r < 4; r++) v[sf * 4 + r] = acc[sf][j][r] * scale;
      float mx = m[j];
#pragma unroll
      for (int t = 0; t < 8; t++) mx = fmaxf(mx, v[t]);
      float sum = 0.f;
#pragma unroll
      for (int t = 0; t < 8; t++) sum += __expf(v[t] - mx);
      zz[j] = zz[j] * __expf(m[j] - mx) + sum;
      m[j] = mx;
    }
  }
#pragma unroll
  for (int j = 0; j < 4; j++) {
    float mj = m[j], zj = zz[j];
#pragma unroll
    for (int off = 16; off <= 32; off <<= 1) {
      float om = __shfl_xor(mj, off, 64);
      float oz = __shfl_xor(zj, off, 64);
      float mn = fmaxf(mj, om);
      zj = zj * __expf(mj - mn) + oz * __expf(om - mn);
      mj = mn;
    }
    if (l < 16) c[(size_t)z * S_ + tb + j * 16 + lr] = mj + __logf(zj);
  }
}

// ---------------- fused attention + output projection ----------------
// out[b, h*S+s, e] = sum_t exp(scale*q.k - c_t) * G[t][e] + bo[e]
// grid (8 sblk, 4 eblk, B*H), block 256. 2 barriers/iter, async staging:
//   loop top: ds_write K(i+1) [dbuf], issue K load(i+2), QK(i)->Ps
//   bar1; PV(i) reads Ps+Gs; bar2; ds_write Gs(i+1), issue G load(i+2)
__launch_bounds__(256, 2)
__global__ void attn_kernel(const unsigned short* __restrict__ Qb,
                            const unsigned short* __restrict__ Kb,
                            const unsigned short* __restrict__ Gt,   // tiled
                            const float* __restrict__ cst,           // [B*H][S]
                            const float* __restrict__ bo,
                            float* __restrict__ out) {
  int sblk = blockIdx.x, eblk = blockIdx.y, z = blockIdx.z;
  int b = z >> 4, h = z & 15;
  __shared__ unsigned short Ks[2][32][72];
  __shared__ unsigned short Gs[256][40];
  __shared__ unsigned short Ps[128][40];
  int tid = threadIdx.x, l = tid & 63, w = tid >> 6;
  int lr = l & 15, lg = l >> 4;
  int ws = w & 1, we = w >> 1;
  const unsigned short* Q = Qb + (size_t)z * S_ * D_ + (size_t)sblk * 128 * D_;
  const unsigned short* K = Kb + (size_t)z * S_ * D_;
  const unsigned short* Gb = Gt + (((size_t)b * 4 + eblk) * 32) * 8192;
  const float* cz = cst + (size_t)z * S_;
  const float scale = 0.125f;

  // Q fragments in registers: wave w owns QK for s rows [w*32, w*32+32)
  bf16x8 q[2][2];
#pragma unroll
  for (int sf = 0; sf < 2; sf++)
#pragma unroll
    for (int ks = 0; ks < 2; ks++)
      q[sf][ks] = *reinterpret_cast<const bf16x8*>(
          Q + (size_t)(w * 32 + sf * 16 + lr) * D_ + ks * 32 + lg * 8);

  int krow = tid >> 3, kc8 = (tid & 7) * 8;
  u16x8 kreg, greg[4];

  // prologue: tile 0 -> LDS; tile 1 -> regs
  kreg = *reinterpret_cast<const u16x8*>(K + (size_t)krow * D_ + kc8);
#pragma unroll
  for (int i = 0; i < 4; i++)
    greg[i] = *reinterpret_cast<const u16x8*>(Gb + (tid + 256 * i) * 8);
  *reinterpret_cast<u16x8*>(&Ks[0][krow][kc8]) = kreg;
#pragma unroll
  for (int i = 0; i < 4; i++) {
    int cid = tid + 256 * i;
    *reinterpret_cast<u16x8*>(&Gs[cid >> 2][(cid & 3) * 8]) = greg[i];
  }
  kreg = *reinterpret_cast<const u16x8*>(K + (size_t)(32 + krow) * D_ + kc8);
#pragma unroll
  for (int i = 0; i < 4; i++)
    greg[i] = *reinterpret_cast<const u16x8*>(Gb + 8192 + (tid + 256 * i) * 8);
  __syncthreads();

  f32x4 acc[4][8] = {};

  for (int it = 0; it < 32; ++it) {
    int cur = it & 1, nxt = cur ^ 1;
    int t0 = it * 32;
    // stage K(i+1) into other buffer; issue K load (i+2)
    *reinterpret_cast<u16x8*>(&Ks[nxt][krow][kc8]) = kreg;
    {
      int tk = t0 + 64; if (tk >= S_) tk = 0;
      kreg = *reinterpret_cast<const u16x8*>(K + (size_t)(tk + krow) * D_ + kc8);
    }
    {  // QK: scores^T, lane holds 4 consecutive t for one s
      bf16x8 ka[2][2];
#pragma unroll
      for (int tf = 0; tf < 2; tf++)
#pragma unroll
        for (int ks = 0; ks < 2; ks++)
          ka[tf][ks] = *reinterpret_cast<const bf16x8*>(&Ks[cur][tf * 16 + lr][ks * 32 + lg * 8]);
      f32x4 sa[2][2] = {};
#pragma unroll
      for (int tf = 0; tf < 2; tf++)
#pragma unroll
        for (int sf = 0; sf < 2; sf++) {
          sa[tf][sf] = MFMA16(ka[tf][0], q[sf][0], sa[tf][sf]);
          sa[tf][sf] = MFMA16(ka[tf][1], q[sf][1], sa[tf][sf]);
        }
#pragma unroll
      for (int tf = 0; tf < 2; tf++) {
        f32x4 cv = *reinterpret_cast<const f32x4*>(cz + t0 + tf * 16 + lg * 4);
#pragma unroll
        for (int sf = 0; sf < 2; sf++) {
          u16x4 p;
#pragma unroll
          for (int r = 0; r < 4; r++)
            p[r] = f2bf(__expf(sa[tf][sf][r] * scale - cv[r]));
          *reinterpret_cast<u16x4*>(&Ps[w * 32 + sf * 16 + lr][tf * 16 + lg * 4]) = p;
        }
      }
    }
    __syncthreads();  // bar1: Ps ready; Ks[nxt] written
    {  // PV: wave (ws,we) owns s [ws*64,+64) x e [we*128,+128)
      bf16x8 ap[4], bg[8];
#pragma unroll
      for (int i = 0; i < 4; i++)
        ap[i] = *reinterpret_cast<const bf16x8*>(&Ps[ws * 64 + i * 16 + lr][lg * 8]);
#pragma unroll
      for (int j = 0; j < 8; j++)
        bg[j] = *reinterpret_cast<const bf16x8*>(&Gs[we * 128 + j * 16 + lr][lg * 8]);
      __builtin_amdgcn_s_setprio(1);
#pragma unroll
      for (int i = 0; i < 4; i++)
#pragma unroll
        for (int j = 0; j < 8; j++)
          acc[i][j] = MFMA16(ap[i], bg[j], acc[i][j]);
      __builtin_amdgcn_s_setprio(0);
    }
    __syncthreads();  // bar2: Gs/Ps reads done, safe to overwrite
    {  // stage G(i+1); issue G loads (i+2)
#pragma unroll
      for (int i = 0; i < 4; i++) {
        int cid = tid + 256 * i;
        *reinterpret_cast<u16x8*>(&Gs[cid >> 2][(cid & 3) * 8]) = greg[i];
      }
      int tg = (it + 2) & 31;
#pragma unroll
      for (int i = 0; i < 4; i++)
        greg[i] = *reinterpret_cast<const u16x8*>(Gb + (size_t)tg * 8192 + (tid + 256 * i) * 8);
    }
  }

  // epilogue: out[b][h*S + s][e] = acc + bo[e]
  float bov[8];
#pragma unroll
  for (int j = 0; j < 8; j++) bov[j] = bo[eblk * 256 + we * 128 + j * 16 + lr];
#pragma unroll
  for (int i = 0; i < 4; i++)
#pragma unroll
    for (int j = 0; j < 8; j++)
#pragma unroll
      for (int r = 0; r < 4; r++) {
        int srow = sblk * 128 + ws * 64 + i * 16 + lg * 4 + r;
        size_t R = (size_t)h * S_ + srow;
        int col = eblk * 256 + we * 128 + j * 16 + lr;
        out[((size_t)b * (H_ * S_) + R) * E_ + col] = acc[i][j][r] + bov[j];
      }
}

extern "C" void kernel_launch(void* const* d_in, const int* in_sizes, int n_in,
                              void* d_out, int out_size, void* d_ws, size_t ws_size,
                              hipStream_t stream) {
  const float* h  = (const float*)d_in[0];
  const float* Wq = (const float*)d_in[1];
  const float* bq = (const float*)d_in[2];
  const float* Wk = (const float*)d_in[3];
  const float* bk = (const float*)d_in[4];
  // d_in[5] = Wv, d_in[6] = bv: dead weights in the reference
  const float* Wo = (const float*)d_in[7];
  const float* bo = (const float*)d_in[8];
  float* out = (float*)d_out;

  char* p = (char*)d_ws;
  unsigned short* hb  = (unsigned short*)p; p += (size_t)B_ * S_ * E_ * 2;
  unsigned short* WoT = (unsigned short*)p; p += (size_t)E_ * E_ * 2;
  unsigned short* WqT = (unsigned short*)p; p += (size_t)H_ * D_ * E_ * 2;
  unsigned short* WkT = (unsigned short*)p; p += (size_t)H_ * D_ * E_ * 2;
  unsigned short* Qb  = (unsigned short*)p; p += (size_t)B_ * H_ * S_ * D_ * 2;
  unsigned short* Kb  = (unsigned short*)p; p += (size_t)B_ * H_ * S_ * D_ * 2;
  unsigned short* Gt  = (unsigned short*)p; p += (size_t)B_ * E_ * S_ * 2;
  float*          cst = (float*)p;          p += (size_t)B_ * H_ * S_ * 4;

  int n4 = B_ * S_ * E_ / 4;
  cast_f32_bf16_kernel<<<dim3(n4 / 256), 256, 0, stream>>>(h, hb, n4);
  transpose_cast_kernel<<<dim3(16, 16, 1), 256, 0, stream>>>(Wo, WoT, E_, E_);
  transpose_cast_kernel<<<dim3(1, 16, H_), 256, 0, stream>>>(Wq, WqT, E_, D_);
  transpose_cast_kernel<<<dim3(1, 16, H_), 256, 0, stream>>>(Wk, WkT, E_, D_);
  gemm_G_kernel<<<dim3(8, 8, B_), 256, 0, stream>>>(hb, WoT, Gt);
  proj_qk_kernel<<<dim3(8, B_ * H_), 256, 0, stream>>>(hb, WqT, WkT, bq, bk, Qb, Kb);
  stats_kernel<<<dim3(S_ / 256, B_ * H_), 256, 0, stream>>>(Qb, Kb, cst);
  attn_kernel<<<dim3(8, 4, B_ * H_), 256, 0, stream>>>(Qb, Kb, Gt, cst, bo, out);
}